// Round 3
// baseline (159.145 us; speedup 1.0000x reference)
//
#include <hip/hip_runtime.h>

// ws layout (floats): [0, nb*8)   per-block partials (s1[4], s2[4])
//                     [nb*8, ...) per-block completion flags (as uint32 MAGIC)
// No zero-init dependency: flags are release-stored each run; partials are
// bitwise-identical across iterations so even a stale flag pass is benign.
#define MAGIC 0x9E3779B9u

__device__ __forceinline__ constexpr int tri(int i, int j){
  return 16*i - (i*(i-1))/2 + (j - i);
}

// ---------------------------------------------------------------------------
// k_main: single-dispatch fusion of circuit-precompute + main pass + stats +
// normalization, using a manual agent-scope flag barrier (all 512 blocks are
// co-resident: 4 waves/block, grid = 2 blocks/CU vs capacity 8).
// ---------------------------------------------------------------------------
__global__ __launch_bounds__(256, 2) void k_main(const float* __restrict__ x,
                                                 const float* __restrict__ W,
                                                 float* __restrict__ qout,
                                                 float* __restrict__ ws,
                                                 const float* __restrict__ gamma,
                                                 const float* __restrict__ beta,
                                                 float invB, int nb){
  __shared__ float Ur[16][16];
  __shared__ float Uim[16][16];
  __shared__ float As[544];
  __shared__ float wred[4][8];
  __shared__ float tot[8];
  const int t = threadIdx.x;
  const size_t row = (size_t)blockIdx.x*256 + t;
  const float4* rp = (const float4*)(x + row*144);

  float* partials = ws;
  unsigned* flags = (unsigned*)(ws + (size_t)nb*8);

  // ---- circuit sim: wave 0, lanes 0-15 (waves 1-3 proceed to pooling) ----
  if (t < 16){
    float re[16], im[16];
    #pragma unroll
    for (int i = 0; i < 16; i++){ re[i] = 0.f; im[i] = 0.f; }
    re[t] = 1.f;

    #pragma unroll
    for (int l = 0; l < 2; l++){
      #pragma unroll
      for (int w = 0; w < 4; w++){
        const int m = 8 >> w;
        const float* g = W + (l*4 + w)*3;
        {
          float th = 0.5f*g[0], c = cosf(th), s = sinf(th);
          #pragma unroll
          for (int i0 = 0; i0 < 16; i0++) if (!(i0 & m)){
            int i1 = i0 | m;
            float a0r=re[i0], a0i=im[i0], a1r=re[i1], a1i=im[i1];
            re[i0] = c*a0r + s*a1i;  im[i0] = c*a0i - s*a1r;
            re[i1] = c*a1r + s*a0i;  im[i1] = c*a1i - s*a0r;
          }
        }
        {
          float th = 0.5f*g[1], c = cosf(th), s = sinf(th);
          #pragma unroll
          for (int i0 = 0; i0 < 16; i0++) if (!(i0 & m)){
            int i1 = i0 | m;
            float a0r=re[i0], a0i=im[i0], a1r=re[i1], a1i=im[i1];
            re[i0] = c*a0r - s*a1r;  im[i0] = c*a0i - s*a1i;
            re[i1] = s*a0r + c*a1r;  im[i1] = s*a0i + c*a1i;
          }
        }
        {
          float th = 0.5f*g[2], c = cosf(th), s = sinf(th);
          #pragma unroll
          for (int i0 = 0; i0 < 16; i0++) if (!(i0 & m)){
            int i1 = i0 | m;
            float a0r=re[i0], a0i=im[i0], a1r=re[i1], a1i=im[i1];
            re[i0] = c*a0r + s*a0i;  im[i0] = c*a0i - s*a0r;
            re[i1] = c*a1r - s*a1i;  im[i1] = c*a1i + s*a1r;
          }
        }
      }
      #pragma unroll
      for (int w = 0; w < 4; w++){
        const int mc = 8 >> w, mt = 8 >> ((w+1)&3);
        float nr[16], ni[16];
        #pragma unroll
        for (int i = 0; i < 16; i++){
          int src = (i & mc) ? (i ^ mt) : i;
          nr[i] = re[src]; ni[i] = im[src];
        }
        #pragma unroll
        for (int i = 0; i < 16; i++){ re[i] = nr[i]; im[i] = ni[i]; }
      }
    }
    #pragma unroll
    for (int k = 0; k < 16; k++){ Ur[k][t] = re[k]; Uim[k][t] = im[k]; }
  }

  // ---- pooling: quadrant sums, fully static mapping (all threads) ----
  float aTL = 0.f, aTR = 0.f, aBL = 0.f, aBR = 0.f;
  #pragma unroll
  for (int ph = 0; ph < 3; ph++){
    float4 buf[12];
    #pragma unroll
    for (int j = 0; j < 12; j++) buf[j] = rp[ph*12 + j];
    #pragma unroll
    for (int j = 0; j < 12; j++){
      const int p  = ph*12 + j;
      const int cg = p % 3;
      float s01 = buf[j].x + buf[j].y, s23 = buf[j].z + buf[j].w;
      float L = (cg == 0) ? (s01 + s23) : ((cg == 1) ? s01 : 0.f);
      float R = (cg == 2) ? (s01 + s23) : ((cg == 1) ? s23 : 0.f);
      if (p < 18){ aTL += L; aTR += R; } else { aBL += L; aBR += R; }
    }
  }

  __syncthreads();   // Ur/Uim ready

  // ---- A build: thread (i=t>>4, j=t&15), i<=j -> 4 wire values into LDS ----
  {
    const int i = t >> 4, j = t & 15;
    if (i <= j){
      const int d = (__popc(i) - __popc(j)) & 3;
      const int n = tri(i, j);
      #pragma unroll
      for (int w = 0; w < 4; w++){
        const int zm = 8 >> w;
        float mr = 0.f, mi = 0.f;
        #pragma unroll
        for (int k = 0; k < 16; k++){
          float z = (k & zm) ? -1.f : 1.f;
          float uir = Ur[k][i], uii = Uim[k][i];
          float ujr = Ur[k][j], uji = Uim[k][j];
          mr += z*(uir*ujr + uii*uji);
          mi += z*(uir*uji - uii*ujr);
        }
        float v = (d == 0) ? mr : (d == 1) ? -mi : (d == 2) ? -mr : mi;
        if (i != j) v *= 2.f;
        As[n*4 + w] = v;
      }
    }
  }
  __syncthreads();   // As ready

  // ---- half-angles, cos/sin (wire order = pooled order: TL,TR,BL,BR) ----
  const float inv = 1.f/72.f;
  float s0,c0,s1,c1,s2,c2,s3,c3;
  __sincosf(aTL*inv, &s0, &c0);
  __sincosf(aTR*inv, &s1, &c1);
  __sincosf(aBL*inv, &s2, &c2);
  __sincosf(aBR*inv, &s3, &c3);

  // r_i = prod_w (bit(i,w) ? s_w : c_w), bit(i,w) = (i>>(3-w))&1
  float t00=c0*c1, t01=c0*s1, t10=s0*c1, t11=s0*s1;
  float u00=c2*c3, u01=c2*s3, u10=s2*c3, u11=s2*s3;
  float r[16];
  r[ 0]=t00*u00; r[ 1]=t00*u01; r[ 2]=t00*u10; r[ 3]=t00*u11;
  r[ 4]=t01*u00; r[ 5]=t01*u01; r[ 6]=t01*u10; r[ 7]=t01*u11;
  r[ 8]=t10*u00; r[ 9]=t10*u01; r[10]=t10*u10; r[11]=t10*u11;
  r[12]=t11*u00; r[13]=t11*u01; r[14]=t11*u10; r[15]=t11*u11;

  // q_w = sum_{i<=j} A_w[n(i,j)] * r_i r_j  -- wave-uniform compile-time LDS
  // addresses -> ds_read_b128 broadcast (conflict-free same-address reads)
  float q0=0.f, q1=0.f, q2=0.f, q3=0.f;
  #pragma unroll
  for (int i = 0; i < 16; i++){
    #pragma unroll
    for (int j = i; j < 16; j++){
      const float4 a4 = *(const float4*)&As[tri(i, j)*4];
      float pij = r[i]*r[j];
      q0 = fmaf(a4.x, pij, q0);
      q1 = fmaf(a4.y, pij, q1);
      q2 = fmaf(a4.z, pij, q2);
      q3 = fmaf(a4.w, pij, q3);
    }
  }

  // ---- block reduction of sum/sumsq for the 4 wires ----
  float red[8] = {q0, q1, q2, q3, q0*q0, q1*q1, q2*q2, q3*q3};
  #pragma unroll
  for (int off = 32; off >= 1; off >>= 1){
    #pragma unroll
    for (int k = 0; k < 8; k++) red[k] += __shfl_down(red[k], off, 64);
  }
  const int lane = t & 63, wv = t >> 6;
  if (lane == 0){
    #pragma unroll
    for (int k = 0; k < 8; k++) wred[wv][k] = red[k];
  }
  __syncthreads();   // wred ready

  // ---- publish this block's partials: 8 relaxed stores + 1 release flag,
  // all by thread 0 (single-thread ordering makes release correct) ----
  if (t == 0){
    #pragma unroll
    for (int k = 0; k < 8; k++){
      float s = wred[0][k] + wred[1][k] + wred[2][k] + wred[3][k];
      __hip_atomic_store(&partials[(size_t)blockIdx.x*8 + k], s,
                         __ATOMIC_RELAXED, __HIP_MEMORY_SCOPE_AGENT);
    }
    __hip_atomic_store(&flags[blockIdx.x], MAGIC,
                       __ATOMIC_RELEASE, __HIP_MEMORY_SCOPE_AGENT);
  }
  __syncthreads();   // t0 done reading wred before we overwrite it below

  // ---- all-to-all: every block redundantly reduces all nb partials.
  // thread t handles source blocks b = t, t+256 (same order as old k_stats) ----
  #pragma unroll
  for (int k = 0; k < 8; k++) red[k] = 0.f;
  for (int b = t; b < nb; b += 256){
    while (__hip_atomic_load(&flags[b], __ATOMIC_ACQUIRE,
                             __HIP_MEMORY_SCOPE_AGENT) != MAGIC) { }
    #pragma unroll
    for (int k = 0; k < 8; k++)
      red[k] += __hip_atomic_load(&partials[(size_t)b*8 + k],
                                  __ATOMIC_RELAXED, __HIP_MEMORY_SCOPE_AGENT);
  }
  #pragma unroll
  for (int off = 32; off >= 1; off >>= 1){
    #pragma unroll
    for (int k = 0; k < 8; k++) red[k] += __shfl_down(red[k], off, 64);
  }
  if (lane == 0){
    #pragma unroll
    for (int k = 0; k < 8; k++) wred[wv][k] = red[k];
  }
  __syncthreads();
  if (t < 8) tot[t] = wred[0][t] + wred[1][t] + wred[2][t] + wred[3][t];
  __syncthreads();

  // ---- scale/shift, normalize register-resident q, single coalesced store ----
  float sc[4], sh[4];
  #pragma unroll
  for (int w = 0; w < 4; w++){
    float mean  = tot[w] * invB;
    float var   = tot[4+w] * invB - mean*mean;
    float scale = gamma[w] * rsqrtf(var + 1e-5f);
    sc[w] = scale;
    sh[w] = fmaf(-mean, scale, beta[w]);
  }
  float4 qv;
  qv.x = fmaf(q0, sc[0], sh[0]);
  qv.y = fmaf(q1, sc[1], sh[1]);
  qv.z = fmaf(q2, sc[2], sh[2]);
  qv.w = fmaf(q3, sc[3], sh[3]);
  ((float4*)qout)[row] = qv;
}

// ---------------------------------------------------------------------------
extern "C" void kernel_launch(void* const* d_in, const int* in_sizes, int n_in,
                              void* d_out, int out_size, void* d_ws, size_t ws_size,
                              hipStream_t stream){
  const float* x     = (const float*)d_in[0];
  const float* W     = (const float*)d_in[1];
  const float* gamma = (const float*)d_in[2];
  const float* beta  = (const float*)d_in[3];
  float* ws  = (float*)d_ws;
  float* out = (float*)d_out;
  const int B  = in_sizes[0] / 144;
  const int nb = B / 256;

  k_main<<<nb, 256, 0, stream>>>(x, W, out, ws, gamma, beta, 1.f/(float)B, nb);
}

// Round 4
// 133.515 us; speedup vs baseline: 1.1920x; 1.1920x over previous
//
#include <hip/hip_runtime.h>

// ws layout (floats): [0, nb*8)   per-block partials (s1[4], s2[4])
//                     [nb*8, ...) per-block completion flags (as uint32 MAGIC)
// Flags are release-stored each iteration; the harness re-poisons ws between
// iterations (verified round 3), so stale-MAGIC cannot occur.
#define MAGIC 0x9E3779B9u

__device__ __forceinline__ constexpr int tri(int i, int j){
  return 16*i - (i*(i-1))/2 + (j - i);
}

// ---------------------------------------------------------------------------
// k_main: single-dispatch fusion (circuit precompute + main pass + stats +
// norm) with a POLITE flag barrier: only wave 0 polls (8 flags/lane) with
// s_sleep backoff -- round 3's 87us was self-inflicted: 131k threads in a
// zero-backoff agent-scope poll loop saturated the fabric and starved the
// x-streaming loads (hbm collapsed to ~450 GB/s).
// ---------------------------------------------------------------------------
__global__ __launch_bounds__(256, 2) void k_main(const float* __restrict__ x,
                                                 const float* __restrict__ W,
                                                 float* __restrict__ qout,
                                                 float* __restrict__ ws,
                                                 const float* __restrict__ gamma,
                                                 const float* __restrict__ beta,
                                                 float invB, int nb){
  __shared__ float Ur[16][16];
  __shared__ float Uim[16][16];
  __shared__ float As[544];
  __shared__ float wred[4][8];
  __shared__ float tot[8];
  const int t = threadIdx.x;
  const size_t row = (size_t)blockIdx.x*256 + t;
  const float4* rp = (const float4*)(x + row*144);

  float* partials = ws;
  unsigned* flags = (unsigned*)(ws + (size_t)nb*8);

  // ---- circuit sim: wave 0, lanes 0-15 (waves 1-3 proceed to pooling) ----
  if (t < 16){
    float re[16], im[16];
    #pragma unroll
    for (int i = 0; i < 16; i++){ re[i] = 0.f; im[i] = 0.f; }
    re[t] = 1.f;

    #pragma unroll
    for (int l = 0; l < 2; l++){
      #pragma unroll
      for (int w = 0; w < 4; w++){
        const int m = 8 >> w;
        const float* g = W + (l*4 + w)*3;
        {
          float th = 0.5f*g[0], c = cosf(th), s = sinf(th);
          #pragma unroll
          for (int i0 = 0; i0 < 16; i0++) if (!(i0 & m)){
            int i1 = i0 | m;
            float a0r=re[i0], a0i=im[i0], a1r=re[i1], a1i=im[i1];
            re[i0] = c*a0r + s*a1i;  im[i0] = c*a0i - s*a1r;
            re[i1] = c*a1r + s*a0i;  im[i1] = c*a1i - s*a0r;
          }
        }
        {
          float th = 0.5f*g[1], c = cosf(th), s = sinf(th);
          #pragma unroll
          for (int i0 = 0; i0 < 16; i0++) if (!(i0 & m)){
            int i1 = i0 | m;
            float a0r=re[i0], a0i=im[i0], a1r=re[i1], a1i=im[i1];
            re[i0] = c*a0r - s*a1r;  im[i0] = c*a0i - s*a1i;
            re[i1] = s*a0r + c*a1r;  im[i1] = s*a0i + c*a1i;
          }
        }
        {
          float th = 0.5f*g[2], c = cosf(th), s = sinf(th);
          #pragma unroll
          for (int i0 = 0; i0 < 16; i0++) if (!(i0 & m)){
            int i1 = i0 | m;
            float a0r=re[i0], a0i=im[i0], a1r=re[i1], a1i=im[i1];
            re[i0] = c*a0r + s*a0i;  im[i0] = c*a0i - s*a0r;
            re[i1] = c*a1r - s*a1i;  im[i1] = c*a1i + s*a1r;
          }
        }
      }
      #pragma unroll
      for (int w = 0; w < 4; w++){
        const int mc = 8 >> w, mt = 8 >> ((w+1)&3);
        float nr[16], ni[16];
        #pragma unroll
        for (int i = 0; i < 16; i++){
          int src = (i & mc) ? (i ^ mt) : i;
          nr[i] = re[src]; ni[i] = im[src];
        }
        #pragma unroll
        for (int i = 0; i < 16; i++){ re[i] = nr[i]; im[i] = ni[i]; }
      }
    }
    #pragma unroll
    for (int k = 0; k < 16; k++){ Ur[k][t] = re[k]; Uim[k][t] = im[k]; }
  }

  // ---- pooling: quadrant sums, fully static mapping (all threads) ----
  float aTL = 0.f, aTR = 0.f, aBL = 0.f, aBR = 0.f;
  #pragma unroll
  for (int ph = 0; ph < 3; ph++){
    float4 buf[12];
    #pragma unroll
    for (int j = 0; j < 12; j++) buf[j] = rp[ph*12 + j];
    #pragma unroll
    for (int j = 0; j < 12; j++){
      const int p  = ph*12 + j;
      const int cg = p % 3;
      float s01 = buf[j].x + buf[j].y, s23 = buf[j].z + buf[j].w;
      float L = (cg == 0) ? (s01 + s23) : ((cg == 1) ? s01 : 0.f);
      float R = (cg == 2) ? (s01 + s23) : ((cg == 1) ? s23 : 0.f);
      if (p < 18){ aTL += L; aTR += R; } else { aBL += L; aBR += R; }
    }
  }

  __syncthreads();   // Ur/Uim ready

  // ---- A build: thread (i=t>>4, j=t&15), i<=j -> 4 wire values into LDS ----
  {
    const int i = t >> 4, j = t & 15;
    if (i <= j){
      const int d = (__popc(i) - __popc(j)) & 3;
      const int n = tri(i, j);
      #pragma unroll
      for (int w = 0; w < 4; w++){
        const int zm = 8 >> w;
        float mr = 0.f, mi = 0.f;
        #pragma unroll
        for (int k = 0; k < 16; k++){
          float z = (k & zm) ? -1.f : 1.f;
          float uir = Ur[k][i], uii = Uim[k][i];
          float ujr = Ur[k][j], uji = Uim[k][j];
          mr += z*(uir*ujr + uii*uji);
          mi += z*(uir*uji - uii*ujr);
        }
        float v = (d == 0) ? mr : (d == 1) ? -mi : (d == 2) ? -mr : mi;
        if (i != j) v *= 2.f;
        As[n*4 + w] = v;
      }
    }
  }
  __syncthreads();   // As ready

  // ---- half-angles, cos/sin (wire order = pooled order: TL,TR,BL,BR) ----
  const float inv = 1.f/72.f;
  float s0,c0,s1,c1,s2,c2,s3,c3;
  __sincosf(aTL*inv, &s0, &c0);
  __sincosf(aTR*inv, &s1, &c1);
  __sincosf(aBL*inv, &s2, &c2);
  __sincosf(aBR*inv, &s3, &c3);

  // r_i = prod_w (bit(i,w) ? s_w : c_w), bit(i,w) = (i>>(3-w))&1
  float t00=c0*c1, t01=c0*s1, t10=s0*c1, t11=s0*s1;
  float u00=c2*c3, u01=c2*s3, u10=s2*c3, u11=s2*s3;
  float r[16];
  r[ 0]=t00*u00; r[ 1]=t00*u01; r[ 2]=t00*u10; r[ 3]=t00*u11;
  r[ 4]=t01*u00; r[ 5]=t01*u01; r[ 6]=t01*u10; r[ 7]=t01*u11;
  r[ 8]=t10*u00; r[ 9]=t10*u01; r[10]=t10*u10; r[11]=t10*u11;
  r[12]=t11*u00; r[13]=t11*u01; r[14]=t11*u10; r[15]=t11*u11;

  // q_w = sum_{i<=j} A_w[n(i,j)] * r_i r_j  -- wave-uniform compile-time LDS
  // addresses -> ds_read_b128 broadcast (conflict-free same-address reads)
  float q0=0.f, q1=0.f, q2=0.f, q3=0.f;
  #pragma unroll
  for (int i = 0; i < 16; i++){
    #pragma unroll
    for (int j = i; j < 16; j++){
      const float4 a4 = *(const float4*)&As[tri(i, j)*4];
      float pij = r[i]*r[j];
      q0 = fmaf(a4.x, pij, q0);
      q1 = fmaf(a4.y, pij, q1);
      q2 = fmaf(a4.z, pij, q2);
      q3 = fmaf(a4.w, pij, q3);
    }
  }

  // ---- block reduction of sum/sumsq for the 4 wires ----
  float red[8] = {q0, q1, q2, q3, q0*q0, q1*q1, q2*q2, q3*q3};
  #pragma unroll
  for (int off = 32; off >= 1; off >>= 1){
    #pragma unroll
    for (int k = 0; k < 8; k++) red[k] += __shfl_down(red[k], off, 64);
  }
  const int lane = t & 63, wv = t >> 6;
  if (lane == 0){
    #pragma unroll
    for (int k = 0; k < 8; k++) wred[wv][k] = red[k];
  }
  __syncthreads();   // wred ready

  // ---- publish this block's partials: 8 relaxed stores + 1 release flag ----
  if (t == 0){
    #pragma unroll
    for (int k = 0; k < 8; k++){
      float s = wred[0][k] + wred[1][k] + wred[2][k] + wred[3][k];
      __hip_atomic_store(&partials[(size_t)blockIdx.x*8 + k], s,
                         __ATOMIC_RELAXED, __HIP_MEMORY_SCOPE_AGENT);
    }
    __hip_atomic_store(&flags[blockIdx.x], MAGIC,
                       __ATOMIC_RELEASE, __HIP_MEMORY_SCOPE_AGENT);
  }

  // ---- polite barrier: ONLY wave 0 polls (8 flags/lane), s_sleep backoff.
  // Relaxed polls; one fence below pairs with the publishers' releases. ----
  if (t < 64){
    for (int b = t; b < nb; b += 64){
      while (__hip_atomic_load(&flags[b], __ATOMIC_RELAXED,
                               __HIP_MEMORY_SCOPE_AGENT) != MAGIC){
        __builtin_amdgcn_s_sleep(8);
      }
    }
    __threadfence();   // acquire: all published partials now visible
  }
  __syncthreads();     // whole block ordered after the fence

  // ---- all-to-all reduction of partials (same order as old k_stats) ----
  #pragma unroll
  for (int k = 0; k < 8; k++) red[k] = 0.f;
  for (int b = t; b < nb; b += 256){
    #pragma unroll
    for (int k = 0; k < 8; k++)
      red[k] += __hip_atomic_load(&partials[(size_t)b*8 + k],
                                  __ATOMIC_RELAXED, __HIP_MEMORY_SCOPE_AGENT);
  }
  #pragma unroll
  for (int off = 32; off >= 1; off >>= 1){
    #pragma unroll
    for (int k = 0; k < 8; k++) red[k] += __shfl_down(red[k], off, 64);
  }
  if (lane == 0){
    #pragma unroll
    for (int k = 0; k < 8; k++) wred[wv][k] = red[k];
  }
  __syncthreads();
  if (t < 8) tot[t] = wred[0][t] + wred[1][t] + wred[2][t] + wred[3][t];
  __syncthreads();

  // ---- scale/shift, normalize register-resident q, single coalesced store ----
  float sc[4], sh[4];
  #pragma unroll
  for (int w = 0; w < 4; w++){
    float mean  = tot[w] * invB;
    float var   = tot[4+w] * invB - mean*mean;
    float scale = gamma[w] * rsqrtf(var + 1e-5f);
    sc[w] = scale;
    sh[w] = fmaf(-mean, scale, beta[w]);
  }
  float4 qv;
  qv.x = fmaf(q0, sc[0], sh[0]);
  qv.y = fmaf(q1, sc[1], sh[1]);
  qv.z = fmaf(q2, sc[2], sh[2]);
  qv.w = fmaf(q3, sc[3], sh[3]);
  ((float4*)qout)[row] = qv;
}

// ---------------------------------------------------------------------------
extern "C" void kernel_launch(void* const* d_in, const int* in_sizes, int n_in,
                              void* d_out, int out_size, void* d_ws, size_t ws_size,
                              hipStream_t stream){
  const float* x     = (const float*)d_in[0];
  const float* W     = (const float*)d_in[1];
  const float* gamma = (const float*)d_in[2];
  const float* beta  = (const float*)d_in[3];
  float* ws  = (float*)d_ws;
  float* out = (float*)d_out;
  const int B  = in_sizes[0] / 144;
  const int nb = B / 256;

  k_main<<<nb, 256, 0, stream>>>(x, W, out, ws, gamma, beta, 1.f/(float)B, nb);
}

// Round 5
// 119.625 us; speedup vs baseline: 1.3304x; 1.1161x over previous
//
#include <hip/hip_runtime.h>

// ws layout: per-block partial sums, 8 floats per block (s1[4], s2[4]), plain
// stores (no atomics, no zero-init dependency). A lives only in LDS.
// NOTE (rounds 1/3/4): every cross-block sync design (cg grid.sync, all-thread
// spin, wave0-spin+s_sleep) costs 45-85 us on MI355X at this grid size --
// the 2-dispatch structure (+~8 us gap) is the proven optimum topology.

__device__ __forceinline__ constexpr int tri(int i, int j){
  return 16*i - (i*(i-1))/2 + (j - i);
}

// ---------------------------------------------------------------------------
// k_main: fused circuit-precompute + main pass (round-2 verified, 120.7 us).
//  wave 0 lanes 0-15: simulate the weights-only circuit U (redundant per
//  block, overlapped with other waves' pooling loads) -> LDS.
//  all threads: A_w = Re(phase * U^dag Z_w U) -> LDS, pooling -> sincos ->
//  q via LDS-broadcast float4 A reads -> coalesced q store -> block
//  reduction -> plain-store 8 partials per block.
// ---------------------------------------------------------------------------
__global__ __launch_bounds__(256) void k_main(const float* __restrict__ x,
                                              const float* __restrict__ W,
                                              float* __restrict__ qout,
                                              float* __restrict__ partials){
  __shared__ float Ur[16][16];
  __shared__ float Uim[16][16];
  __shared__ float As[544];
  __shared__ float wred[4][8];
  const int t = threadIdx.x;
  const size_t row = (size_t)blockIdx.x*256 + t;
  const float4* rp = (const float4*)(x + row*144);

  // ---- circuit sim: wave 0, lanes 0-15 (waves 1-3 proceed to pooling) ----
  if (t < 16){
    float re[16], im[16];
    #pragma unroll
    for (int i = 0; i < 16; i++){ re[i] = 0.f; im[i] = 0.f; }
    re[t] = 1.f;

    #pragma unroll
    for (int l = 0; l < 2; l++){
      #pragma unroll
      for (int w = 0; w < 4; w++){
        const int m = 8 >> w;
        const float* g = W + (l*4 + w)*3;
        {
          float th = 0.5f*g[0], c = cosf(th), s = sinf(th);
          #pragma unroll
          for (int i0 = 0; i0 < 16; i0++) if (!(i0 & m)){
            int i1 = i0 | m;
            float a0r=re[i0], a0i=im[i0], a1r=re[i1], a1i=im[i1];
            re[i0] = c*a0r + s*a1i;  im[i0] = c*a0i - s*a1r;
            re[i1] = c*a1r + s*a0i;  im[i1] = c*a1i - s*a0r;
          }
        }
        {
          float th = 0.5f*g[1], c = cosf(th), s = sinf(th);
          #pragma unroll
          for (int i0 = 0; i0 < 16; i0++) if (!(i0 & m)){
            int i1 = i0 | m;
            float a0r=re[i0], a0i=im[i0], a1r=re[i1], a1i=im[i1];
            re[i0] = c*a0r - s*a1r;  im[i0] = c*a0i - s*a1i;
            re[i1] = s*a0r + c*a1r;  im[i1] = s*a0i + c*a1i;
          }
        }
        {
          float th = 0.5f*g[2], c = cosf(th), s = sinf(th);
          #pragma unroll
          for (int i0 = 0; i0 < 16; i0++) if (!(i0 & m)){
            int i1 = i0 | m;
            float a0r=re[i0], a0i=im[i0], a1r=re[i1], a1i=im[i1];
            re[i0] = c*a0r + s*a0i;  im[i0] = c*a0i - s*a0r;
            re[i1] = c*a1r - s*a1i;  im[i1] = c*a1i + s*a1r;
          }
        }
      }
      #pragma unroll
      for (int w = 0; w < 4; w++){
        const int mc = 8 >> w, mt = 8 >> ((w+1)&3);
        float nr[16], ni[16];
        #pragma unroll
        for (int i = 0; i < 16; i++){
          int src = (i & mc) ? (i ^ mt) : i;
          nr[i] = re[src]; ni[i] = im[src];
        }
        #pragma unroll
        for (int i = 0; i < 16; i++){ re[i] = nr[i]; im[i] = ni[i]; }
      }
    }
    #pragma unroll
    for (int k = 0; k < 16; k++){ Ur[k][t] = re[k]; Uim[k][t] = im[k]; }
  }

  // ---- pooling: quadrant sums, fully static mapping (all threads) ----
  float aTL = 0.f, aTR = 0.f, aBL = 0.f, aBR = 0.f;
  #pragma unroll
  for (int ph = 0; ph < 3; ph++){
    float4 buf[12];
    #pragma unroll
    for (int j = 0; j < 12; j++) buf[j] = rp[ph*12 + j];
    #pragma unroll
    for (int j = 0; j < 12; j++){
      const int p  = ph*12 + j;
      const int cg = p % 3;
      float s01 = buf[j].x + buf[j].y, s23 = buf[j].z + buf[j].w;
      float L = (cg == 0) ? (s01 + s23) : ((cg == 1) ? s01 : 0.f);
      float R = (cg == 2) ? (s01 + s23) : ((cg == 1) ? s23 : 0.f);
      if (p < 18){ aTL += L; aTR += R; } else { aBL += L; aBR += R; }
    }
  }

  __syncthreads();   // Ur/Uim ready

  // ---- A build: thread (i=t>>4, j=t&15), i<=j -> 4 wire values into LDS ----
  {
    const int i = t >> 4, j = t & 15;
    if (i <= j){
      const int d = (__popc(i) - __popc(j)) & 3;
      const int n = tri(i, j);
      #pragma unroll
      for (int w = 0; w < 4; w++){
        const int zm = 8 >> w;
        float mr = 0.f, mi = 0.f;
        #pragma unroll
        for (int k = 0; k < 16; k++){
          float z = (k & zm) ? -1.f : 1.f;
          float uir = Ur[k][i], uii = Uim[k][i];
          float ujr = Ur[k][j], uji = Uim[k][j];
          mr += z*(uir*ujr + uii*uji);
          mi += z*(uir*uji - uii*ujr);
        }
        float v = (d == 0) ? mr : (d == 1) ? -mi : (d == 2) ? -mr : mi;
        if (i != j) v *= 2.f;
        As[n*4 + w] = v;
      }
    }
  }
  __syncthreads();   // As ready

  // ---- half-angles, cos/sin (wire order = pooled order: TL,TR,BL,BR) ----
  const float inv = 1.f/72.f;
  float s0,c0,s1,c1,s2,c2,s3,c3;
  __sincosf(aTL*inv, &s0, &c0);
  __sincosf(aTR*inv, &s1, &c1);
  __sincosf(aBL*inv, &s2, &c2);
  __sincosf(aBR*inv, &s3, &c3);

  // r_i = prod_w (bit(i,w) ? s_w : c_w), bit(i,w) = (i>>(3-w))&1
  float t00=c0*c1, t01=c0*s1, t10=s0*c1, t11=s0*s1;
  float u00=c2*c3, u01=c2*s3, u10=s2*c3, u11=s2*s3;
  float r[16];
  r[ 0]=t00*u00; r[ 1]=t00*u01; r[ 2]=t00*u10; r[ 3]=t00*u11;
  r[ 4]=t01*u00; r[ 5]=t01*u01; r[ 6]=t01*u10; r[ 7]=t01*u11;
  r[ 8]=t10*u00; r[ 9]=t10*u01; r[10]=t10*u10; r[11]=t10*u11;
  r[12]=t11*u00; r[13]=t11*u01; r[14]=t11*u10; r[15]=t11*u11;

  // q_w = sum_{i<=j} A_w[n(i,j)] * r_i r_j  -- wave-uniform compile-time LDS
  // addresses -> ds_read_b128 broadcast (conflict-free same-address reads)
  float q0=0.f, q1=0.f, q2=0.f, q3=0.f;
  #pragma unroll
  for (int i = 0; i < 16; i++){
    #pragma unroll
    for (int j = i; j < 16; j++){
      const float4 a4 = *(const float4*)&As[tri(i, j)*4];
      float pij = r[i]*r[j];
      q0 = fmaf(a4.x, pij, q0);
      q1 = fmaf(a4.y, pij, q1);
      q2 = fmaf(a4.z, pij, q2);
      q3 = fmaf(a4.w, pij, q3);
    }
  }

  ((float4*)qout)[row] = make_float4(q0, q1, q2, q3);   // coalesced 16B/lane

  // block reduction of sum/sumsq for the 4 wires
  float red[8] = {q0, q1, q2, q3, q0*q0, q1*q1, q2*q2, q3*q3};
  #pragma unroll
  for (int off = 32; off >= 1; off >>= 1){
    #pragma unroll
    for (int k = 0; k < 8; k++) red[k] += __shfl_down(red[k], off, 64);
  }
  const int lane = t & 63, wv = t >> 6;
  if (lane == 0){
    #pragma unroll
    for (int k = 0; k < 8; k++) wred[wv][k] = red[k];
  }
  __syncthreads();
  if (t < 8){
    float s = wred[0][t] + wred[1][t] + wred[2][t] + wred[3][t];
    partials[blockIdx.x*8 + t] = s;   // plain store -- no atomics, no init
  }
}

// ---------------------------------------------------------------------------
// k_stats: 256 blocks; each redundantly reduces the nb x 8 partials (16 KB,
// L2-hot, same order as before -> bit-identical stats), computes scale/shift,
// then normalizes 2 float4s of out per thread in place.
// ---------------------------------------------------------------------------
__global__ __launch_bounds__(256) void k_stats(float* __restrict__ out,
                                               const float* __restrict__ partials,
                                               const float* __restrict__ gamma,
                                               const float* __restrict__ beta,
                                               float invB, int nb){
  __shared__ float wred[4][8];
  __shared__ float tot[8];
  const int t = threadIdx.x;

  // strided accumulation of per-block partials (nb=512 -> 2 iters/thread)
  float red[8] = {0.f,0.f,0.f,0.f,0.f,0.f,0.f,0.f};
  const float4* p4 = (const float4*)partials;
  for (int b = t; b < nb; b += 256){
    float4 A0 = p4[b*2+0];
    float4 A1 = p4[b*2+1];
    red[0] += A0.x; red[1] += A0.y; red[2] += A0.z; red[3] += A0.w;
    red[4] += A1.x; red[5] += A1.y; red[6] += A1.z; red[7] += A1.w;
  }
  #pragma unroll
  for (int off = 32; off >= 1; off >>= 1){
    #pragma unroll
    for (int k = 0; k < 8; k++) red[k] += __shfl_down(red[k], off, 64);
  }
  const int lane = t & 63, wv = t >> 6;
  if (lane == 0){
    #pragma unroll
    for (int k = 0; k < 8; k++) wred[wv][k] = red[k];
  }
  __syncthreads();
  if (t < 8) tot[t] = wred[0][t] + wred[1][t] + wred[2][t] + wred[3][t];
  __syncthreads();

  float sc[4], sh[4];
  #pragma unroll
  for (int w = 0; w < 4; w++){
    float mean  = tot[w] * invB;
    float var   = tot[4+w] * invB - mean*mean;
    float scale = gamma[w] * rsqrtf(var + 1e-5f);
    sc[w] = scale;
    sh[w] = fmaf(-mean, scale, beta[w]);
  }

  // 2 coalesced float4s per thread (256 blocks x 256 threads x 2 = 131072)
  float4* o4 = (float4*)out;
  const int base = blockIdx.x*512 + t;
  #pragma unroll
  for (int h = 0; h < 2; h++){
    const int idx = base + h*256;
    float4 qv = o4[idx];
    qv.x = fmaf(qv.x, sc[0], sh[0]);
    qv.y = fmaf(qv.y, sc[1], sh[1]);
    qv.z = fmaf(qv.z, sc[2], sh[2]);
    qv.w = fmaf(qv.w, sc[3], sh[3]);
    o4[idx] = qv;
  }
}

// ---------------------------------------------------------------------------
extern "C" void kernel_launch(void* const* d_in, const int* in_sizes, int n_in,
                              void* d_out, int out_size, void* d_ws, size_t ws_size,
                              hipStream_t stream){
  const float* x     = (const float*)d_in[0];
  const float* W     = (const float*)d_in[1];
  const float* gamma = (const float*)d_in[2];
  const float* beta  = (const float*)d_in[3];
  float* ws  = (float*)d_ws;
  float* out = (float*)d_out;
  const int B  = in_sizes[0] / 144;
  const int nb = B / 256;

  k_main <<<nb,  256, 0, stream>>>(x, W, out, ws);
  k_stats<<<nb/2,256, 0, stream>>>(out, ws, gamma, beta, 1.f/(float)B, nb);
}